// Round 4
// baseline (291.837 us; speedup 1.0000x reference)
//
#include <hip/hip_runtime.h>

#define NROWS 4096
#define NDOM 8

typedef short short8 __attribute__((ext_vector_type(8)));
typedef float floatx4 __attribute__((ext_vector_type(4)));
typedef float floatx2 __attribute__((ext_vector_type(2)));
typedef unsigned uint2v __attribute__((ext_vector_type(2)));

__device__ __forceinline__ unsigned short f2bf(float f) {
    union { float f; unsigned u; } v; v.f = f;
    unsigned r = v.u + 0x7FFFu + ((v.u >> 16) & 1u);  // RNE
    return (unsigned short)(r >> 16);
}

// Deterministic stable counting sort: rowidx is a pure function of `ind`.
// (atomicAdd ordering made rowidx nondeterministic across launches -> stale
//  cross-kernel views could mix permutations. Determinism removes the hazard.)
__global__ void bucket_kernel(const int* __restrict__ ind,
                              int* __restrict__ offsets,
                              int* __restrict__ rowidx) {
    __shared__ unsigned short cnt[256][NDOM];   // per-chunk domain counts (<=16)
    __shared__ int base[256][NDOM];             // exclusive prefix per domain
    __shared__ int dom_total[NDOM];
    __shared__ int dom_off[NDOM + 1];
    const int t = threadIdx.x;                  // chunk id, rows [t*16, t*16+16)

    int myind[16];
#pragma unroll
    for (int i = 0; i < 16; ++i) myind[i] = ind[t * 16 + i];

    unsigned short c[NDOM];
#pragma unroll
    for (int d = 0; d < NDOM; ++d) c[d] = 0;
#pragma unroll
    for (int i = 0; i < 16; ++i) c[myind[i]]++;
#pragma unroll
    for (int d = 0; d < NDOM; ++d) cnt[t][d] = c[d];
    __syncthreads();

    if (t < NDOM) {
        int acc = 0;
        for (int ch = 0; ch < 256; ++ch) { base[ch][t] = acc; acc += cnt[ch][t]; }
        dom_total[t] = acc;
    }
    __syncthreads();
    if (t == 0) {
        int acc = 0;
        for (int d = 0; d < NDOM; ++d) { dom_off[d] = acc; acc += dom_total[d]; }
        dom_off[NDOM] = acc;
    }
    __syncthreads();

    int pos[NDOM];
#pragma unroll
    for (int d = 0; d < NDOM; ++d) pos[d] = dom_off[d] + base[t][d];
#pragma unroll
    for (int i = 0; i < 16; ++i) {
        int dm = myind[i];
        rowidx[pos[dm]++] = t * 16 + i;
    }
    if (t <= NDOM) offsets[t] = dom_off[t];
}

// Grouped GEMM. Block = 256 threads = 2x2 waves; wave tile (FM*16)x(FN*16),
// block tile BM=32*FM x BN=32*FN. Register-pipelined global->LDS staging;
// w_eff = sk*dk fused to bf16, transposed [n][k], chunk-XOR swizzled.
template <int FM, int FN, int MSLOTS, int K, int N, bool GATHER, bool SCATTER>
__launch_bounds__(256)
__global__ void star_gemm(const float* __restrict__ Afp,
                          const unsigned short* __restrict__ Abf,
                          const float* __restrict__ sk,
                          const float* __restrict__ dk,
                          const float* __restrict__ sb,
                          const float* __restrict__ db,
                          float* __restrict__ OutF,
                          unsigned short* __restrict__ OutB,
                          const int* __restrict__ offsets,
                          const int* __restrict__ rowidx) {
    constexpr int BM = 32 * FM;
    constexpr int BN = 32 * FN;
    constexpr int WCOLS = BN / 32;   // n-cols per thread in W staging
    constexpr int AR = BM / 32;      // bf16-A staging rounds
    constexpr int NK = K / 64;
    constexpr int TPR = 256 / BM;    // gather-A: threads per row
    constexpr int KPT = 64 / TPR;    // gather-A: k elems per thread
    constexpr int R4 = KPT / 4;      // gather-A: float4 loads per thread

    __shared__ unsigned short As[BM * 64];
    __shared__ unsigned short Ws[BN * 64];

    const int gid = blockIdx.x;
    const int d = gid & 7;                       // domain -> XCD round-robin
    const int mslot = (gid >> 3) % MSLOTS;
    const int n0 = (gid / (8 * MSLOTS)) * BN;

    const int bstart = offsets[d];
    const int bend = offsets[d + 1];
    const int bsize = bend - bstart;

    const int tid = threadIdx.x;
    const int lane = tid & 63;
    const int wid = tid >> 6;
    const int wy = wid >> 1;
    const int wx = wid & 1;
    const int lm = lane & 15;
    const int quad = lane >> 4;

    float bias[FN];
#pragma unroll
    for (int j = 0; j < FN; ++j) {
        int n = n0 + wx * FN * 16 + j * 16 + lm;
        bias[j] = sb[n] + db[d * N + n];
    }

    // W staging coords: k = wk8*8 + r (r=0..7), n = wn..wn+WCOLS-1
    const int wk8 = tid >> 5;
    const int wn = (tid & 31) * WCOLS;
    const float* skp = sk + (size_t)(wk8 * 8) * N + n0 + wn;
    const float* dkp = dk + ((size_t)d * K + wk8 * 8) * N + n0 + wn;

    // A gather coords
    const int am = tid / TPR;
    const int aq = tid % TPR;

    floatx4 ps[8], pd[8];
    floatx2 ps2[8], pd2[8];
    floatx4 pax[8];
    short8 pab[AR > 0 ? AR : 1];

    for (int mt = mslot; mt * BM < bsize; mt += MSLOTS) {
        const int row_start = bstart + mt * BM;

        const float* ap = nullptr;
        const unsigned short* abp[AR > 0 ? AR : 1];
        if constexpr (GATHER) {
            int p = row_start + am; if (p >= bend) p = bend - 1;  // in-bucket clamp
            ap = Afp + (size_t)rowidx[p] * K + aq * KPT;
        } else {
#pragma unroll
            for (int r = 0; r < AR; ++r) {
                int flat = r * 256 + tid;
                int m = flat >> 3;
                int ch = flat & 7;
                int p = row_start + m; if (p >= bend) p = bend - 1;
                abp[r] = Abf + (size_t)p * K + ch * 8;
            }
        }

        auto issue = [&](int k0) {
            if constexpr (GATHER) {
#pragma unroll
                for (int r = 0; r < R4; ++r)
                    pax[r] = *(const floatx4*)(ap + k0 + r * 4);
            } else {
#pragma unroll
                for (int r = 0; r < AR; ++r)
                    pab[r] = *(const short8*)(abp[r] + k0);
            }
            if constexpr (WCOLS == 4) {
#pragma unroll
                for (int r = 0; r < 8; ++r) {
                    ps[r] = *(const floatx4*)(skp + (size_t)(k0 + r) * N);
                    pd[r] = *(const floatx4*)(dkp + (size_t)(k0 + r) * N);
                }
            } else {
#pragma unroll
                for (int r = 0; r < 8; ++r) {
                    ps2[r] = *(const floatx2*)(skp + (size_t)(k0 + r) * N);
                    pd2[r] = *(const floatx2*)(dkp + (size_t)(k0 + r) * N);
                }
            }
        };

        auto stage = [&]() {
            if constexpr (GATHER) {
#pragma unroll
                for (int r = 0; r < R4; ++r) {
                    int k = aq * KPT + r * 4;
                    unsigned b01 = (unsigned)f2bf(pax[r][0]) | ((unsigned)f2bf(pax[r][1]) << 16);
                    unsigned b23 = (unsigned)f2bf(pax[r][2]) | ((unsigned)f2bf(pax[r][3]) << 16);
                    int phys = (k >> 3) ^ (am & 7);
                    *(uint2v*)&As[am * 64 + phys * 8 + (k & 7)] = uint2v{b01, b23};
                }
            } else {
#pragma unroll
                for (int r = 0; r < AR; ++r) {
                    int flat = r * 256 + tid;
                    int m = flat >> 3;
                    int ch = flat & 7;
                    *(short8*)&As[m * 64 + ((ch ^ (m & 7)) * 8)] = pab[r];
                }
            }
            unsigned short wb[WCOLS][8];
#pragma unroll
            for (int r = 0; r < 8; ++r) {
#pragma unroll
                for (int c = 0; c < WCOLS; ++c) {
                    float v;
                    if constexpr (WCOLS == 4) v = ps[r][c] * pd[r][c];
                    else                      v = ps2[r][c] * pd2[r][c];
                    wb[c][r] = f2bf(v);
                }
            }
#pragma unroll
            for (int c = 0; c < WCOLS; ++c) {
                int nn = wn + c;
                int phys = wk8 ^ (nn & 7);
                *(short8*)&Ws[nn * 64 + phys * 8] = *(short8*)wb[c];
            }
        };

        floatx4 acc[FM][FN];
#pragma unroll
        for (int i = 0; i < FM; ++i)
#pragma unroll
            for (int j = 0; j < FN; ++j) acc[i][j] = floatx4{0.f, 0.f, 0.f, 0.f};

        issue(0);
        for (int kt = 0; kt < NK; ++kt) {
            __syncthreads();               // prev compute done reading LDS
            stage();
            if (kt + 1 < NK) issue((kt + 1) * 64);
            __syncthreads();
#pragma unroll
            for (int kk = 0; kk < 2; ++kk) {
                short8 av[FM], wv[FN];
#pragma unroll
                for (int i = 0; i < FM; ++i) {
                    int m = wy * FM * 16 + i * 16 + lm;
                    int phys = (kk * 4 + quad) ^ (m & 7);
                    av[i] = *(const short8*)&As[m * 64 + phys * 8];
                }
#pragma unroll
                for (int j = 0; j < FN; ++j) {
                    int n = wx * FN * 16 + j * 16 + lm;
                    int phys = (kk * 4 + quad) ^ (n & 7);
                    wv[j] = *(const short8*)&Ws[n * 64 + phys * 8];
                }
#pragma unroll
                for (int i = 0; i < FM; ++i)
#pragma unroll
                    for (int j = 0; j < FN; ++j)
                        acc[i][j] = __builtin_amdgcn_mfma_f32_16x16x32_bf16(
                            av[i], wv[j], acc[i][j], 0, 0, 0);
            }
        }

        // epilogue: bias + relu; C layout col=lane&15, row=quad*4+reg
#pragma unroll
        for (int i = 0; i < FM; ++i) {
#pragma unroll
            for (int rg = 0; rg < 4; ++rg) {
                int m = wy * FM * 16 + i * 16 + quad * 4 + rg;
                int p = row_start + m;
                if (p < bend) {
                    if constexpr (SCATTER) {
                        int orow = rowidx[p];
#pragma unroll
                        for (int j = 0; j < FN; ++j) {
                            int n = n0 + wx * FN * 16 + j * 16 + lm;
                            float v = acc[i][j][rg] + bias[j];
                            OutF[(size_t)orow * N + n] = v > 0.f ? v : 0.f;
                        }
                    } else {
#pragma unroll
                        for (int j = 0; j < FN; ++j) {
                            int n = n0 + wx * FN * 16 + j * 16 + lm;
                            float v = acc[i][j][rg] + bias[j];
                            OutB[(size_t)p * N + n] = f2bf(v > 0.f ? v : 0.f);
                        }
                    }
                }
            }
        }
    }
}

extern "C" void kernel_launch(void* const* d_in, const int* in_sizes, int n_in,
                              void* d_out, int out_size, void* d_ws, size_t ws_size,
                              hipStream_t stream) {
    const float* x = (const float*)d_in[0];
    const int* ind = (const int*)d_in[1];
    const float* sk0 = (const float*)d_in[2];
    const float* sb0 = (const float*)d_in[3];
    const float* dk0 = (const float*)d_in[4];
    const float* db0 = (const float*)d_in[5];
    const float* sk1 = (const float*)d_in[6];
    const float* sb1 = (const float*)d_in[7];
    const float* dk1 = (const float*)d_in[8];
    const float* db1 = (const float*)d_in[9];
    const float* sk2 = (const float*)d_in[10];
    const float* sb2 = (const float*)d_in[11];
    const float* dk2 = (const float*)d_in[12];
    const float* db2 = (const float*)d_in[13];
    float* out = (float*)d_out;

    char* ws = (char*)d_ws;
    int* offsets = (int*)ws;                                   // 9 ints
    int* rowidx = (int*)(ws + 256);                            // 4096 ints
    unsigned short* h1b = (unsigned short*)(ws + 32768);       // 4096x1024 bf16
    unsigned short* h2b = h1b + (size_t)NROWS * 1024;          // 4096x512 bf16

    bucket_kernel<<<1, 256, 0, stream>>>(ind, offsets, rowidx);

    // L0: 64x128 tiles, 8d x 8m x 8n = 512 blocks (2/CU)
    star_gemm<2, 4, 8, 1024, 1024, true, false><<<512, 256, 0, stream>>>(
        x, nullptr, sk0, dk0, sb0, db0, nullptr, h1b, offsets, rowidx);
    // L1: 64x64 tiles, 8d x 8m x 8n = 512 blocks
    star_gemm<2, 2, 8, 1024, 512, false, false><<<512, 256, 0, stream>>>(
        nullptr, h1b, sk1, dk1, sb1, db1, nullptr, h2b, offsets, rowidx);
    // L2: 32x64 tiles, 8d x 16m x 4n = 512 blocks
    star_gemm<1, 2, 16, 512, 256, false, true><<<512, 256, 0, stream>>>(
        nullptr, h2b, sk2, dk2, sb2, db2, out, nullptr, offsets, rowidx);
}

// Round 5
// 206.314 us; speedup vs baseline: 1.4145x; 1.4145x over previous
//
#include <hip/hip_runtime.h>

#define NROWS 4096
#define NDOM 8

typedef short short8 __attribute__((ext_vector_type(8)));
typedef float floatx4 __attribute__((ext_vector_type(4)));
typedef unsigned short ushort4v __attribute__((ext_vector_type(4)));
typedef unsigned short ushort8v __attribute__((ext_vector_type(8)));

__device__ __forceinline__ unsigned short f2bf(float f) {
    union { float f; unsigned u; } v; v.f = f;
    unsigned r = v.u + 0x7FFFu + ((v.u >> 16) & 1u);  // RNE
    return (unsigned short)(r >> 16);
}

// async global->LDS, 16B per lane; dest = wave-uniform base + lane*16
__device__ __forceinline__ void dma16(const void* g, void* l) {
    __builtin_amdgcn_global_load_lds(
        (const __attribute__((address_space(1))) unsigned*)g,
        (__attribute__((address_space(3))) unsigned*)l, 16, 0, 0);
}

// Deterministic stable counting sort: rowidx is a pure function of `ind`.
__global__ void bucket_kernel(const int* __restrict__ ind,
                              int* __restrict__ offsets,
                              int* __restrict__ rowidx) {
    __shared__ unsigned short cnt[256][NDOM];
    __shared__ int base[256][NDOM];
    __shared__ int dom_total[NDOM];
    __shared__ int dom_off[NDOM + 1];
    const int t = threadIdx.x;

    int myind[16];
#pragma unroll
    for (int i = 0; i < 16; ++i) myind[i] = ind[t * 16 + i];

    unsigned short c[NDOM];
#pragma unroll
    for (int d = 0; d < NDOM; ++d) c[d] = 0;
#pragma unroll
    for (int i = 0; i < 16; ++i) c[myind[i]]++;
#pragma unroll
    for (int d = 0; d < NDOM; ++d) cnt[t][d] = c[d];
    __syncthreads();

    if (t < NDOM) {
        int acc = 0;
        for (int ch = 0; ch < 256; ++ch) { base[ch][t] = acc; acc += cnt[ch][t]; }
        dom_total[t] = acc;
    }
    __syncthreads();
    if (t == 0) {
        int acc = 0;
        for (int d = 0; d < NDOM; ++d) { dom_off[d] = acc; acc += dom_total[d]; }
        dom_off[NDOM] = acc;
    }
    __syncthreads();

    int pos[NDOM];
#pragma unroll
    for (int d = 0; d < NDOM; ++d) pos[d] = dom_off[d] + base[t][d];
#pragma unroll
    for (int i = 0; i < 16; ++i) {
        int dm = myind[i];
        rowidx[pos[dm]++] = t * 16 + i;
    }
    if (t <= NDOM) offsets[t] = dom_off[t];
}

// one 64k x 64n tile of w_eff^T = bf16(sk*dk), stored [d][n][k]
template <int K, int N>
__device__ __forceinline__ void weff_tile(const float* __restrict__ sk,
                                          const float* __restrict__ dk,
                                          unsigned short* __restrict__ wt,
                                          int local) {
    const int d = local & 7;
    const int rest = local >> 3;
    const int k0 = (rest % (K / 64)) * 64;
    const int n0 = (rest / (K / 64)) * 64;
    const int t = threadIdx.x;
    const int n = n0 + (t & 63);
    const int koff = k0 + (t >> 6) * 16;
    unsigned short wb[16];
#pragma unroll
    for (int kk = 0; kk < 16; ++kk) {
        int k = koff + kk;
        float s = sk[(size_t)k * N + n];
        float dd = dk[((size_t)d * K + k) * N + n];
        wb[kk] = f2bf(s * dd);
    }
    unsigned short* dst = wt + ((size_t)d * N + n) * K + koff;
    *(ushort8v*)dst = *(ushort8v*)wb;
    *(ushort8v*)(dst + 8) = *(ushort8v*)(wb + 8);
}

__global__ void precompute_kernel(const float* __restrict__ x,
                                  const int* __restrict__ rowidx,
                                  const float* __restrict__ sk0, const float* __restrict__ dk0,
                                  const float* __restrict__ sk1, const float* __restrict__ dk1,
                                  const float* __restrict__ sk2, const float* __restrict__ dk2,
                                  unsigned short* __restrict__ xb,
                                  unsigned short* __restrict__ w0t,
                                  unsigned short* __restrict__ w1t,
                                  unsigned short* __restrict__ w2t) {
    const int b = blockIdx.x;
    if (b < 256) {
        // xb[p][k] = bf16(x[rowidx[p]][k])  (bucket-gathered)
        const int t = threadIdx.x;
#pragma unroll
        for (int r = 0; r < 16; ++r) {
            int p = b * 16 + r;
            int src = rowidx[p];
            floatx4 v = *(const floatx4*)(x + (size_t)src * 1024 + t * 4);
            ushort4v o;
            o[0] = f2bf(v[0]); o[1] = f2bf(v[1]); o[2] = f2bf(v[2]); o[3] = f2bf(v[3]);
            *(ushort4v*)(xb + (size_t)p * 1024 + t * 4) = o;
        }
    } else if (b < 256 + 2048) {
        weff_tile<1024, 1024>(sk0, dk0, w0t, b - 256);
    } else if (b < 256 + 2048 + 1024) {
        weff_tile<1024, 512>(sk1, dk1, w1t, b - (256 + 2048));
    } else {
        weff_tile<512, 256>(sk2, dk2, w2t, b - (256 + 2048 + 1024));
    }
}

// Grouped GEMM, all-DMA staging. Block = 2x2 waves, wave tile (FM*16)x(FN*16).
// A: bucket-ordered bf16 [*, K]; Wt: bf16 [d][n][k]. LDS chunk-XOR swizzle is
// realized on the DMA *source* address (dest is forced lane*16).
template <int FM, int FN, int MSLOTS, int K, int N, bool SCATTER>
__launch_bounds__(256)
__global__ void star_gemm(const unsigned short* __restrict__ Ab,
                          const unsigned short* __restrict__ Wt,
                          const float* __restrict__ sb,
                          const float* __restrict__ db,
                          float* __restrict__ OutF,
                          unsigned short* __restrict__ OutB,
                          const int* __restrict__ offsets,
                          const int* __restrict__ rowidx) {
    constexpr int BM = 32 * FM;
    constexpr int BN = 32 * FN;
    constexpr int NK = K / 64;
    constexpr int AI = BM / 32;   // A dma instrs per wave (1KB each)
    constexpr int WI = BN / 32;   // W dma instrs per wave

    __shared__ __align__(128) unsigned short As[BM * 64];
    __shared__ __align__(128) unsigned short Ws[BN * 64];

    const int gid = blockIdx.x;
    const int d = gid & 7;                     // domain -> XCD round-robin
    const int mslot = (gid >> 3) % MSLOTS;
    const int n0 = (gid / (8 * MSLOTS)) * BN;

    const int bstart = offsets[d];
    const int bend = offsets[d + 1];
    const int bsize = bend - bstart;

    const int tid = threadIdx.x;
    const int lane = tid & 63;
    const int w = tid >> 6;
    const int wy = w >> 1;
    const int wx = w & 1;
    const int lm = lane & 15;
    const int quad = lane >> 4;

    // DMA lane decomposition: lane covers (row lrow, phys chunk phys)
    const int lrow = lane >> 3;
    const int phys = lane & 7;

    float bias[FN];
#pragma unroll
    for (int j = 0; j < FN; ++j) {
        int n = n0 + wx * FN * 16 + j * 16 + lm;
        bias[j] = sb[n] + db[d * N + n];
    }

    // W dma pointers (loop-invariant)
    const unsigned short* wsrc[WI];
    unsigned short* wdst[WI];
#pragma unroll
    for (int j = 0; j < WI; ++j) {
        int nr0 = (w * WI + j) * 8;
        int nn = nr0 + lrow;
        int ch = phys ^ (nn & 7);
        wsrc[j] = Wt + ((size_t)d * N + n0 + nn) * K + ch * 8;
        wdst[j] = Ws + nr0 * 64;   // wave-uniform
    }

    for (int mt = mslot; mt * BM < bsize; mt += MSLOTS) {
        const int row_start = bstart + mt * BM;

        const unsigned short* asrc[AI];
        unsigned short* adst[AI];
#pragma unroll
        for (int j = 0; j < AI; ++j) {
            int m0 = (w * AI + j) * 8;
            int mm = m0 + lrow;
            int ch = phys ^ (mm & 7);
            int p = row_start + mm; if (p >= bend) p = bend - 1;  // in-bucket clamp
            asrc[j] = Ab + (size_t)p * K + ch * 8;
            adst[j] = As + m0 * 64;   // wave-uniform
        }

        floatx4 acc[FM][FN];
#pragma unroll
        for (int i = 0; i < FM; ++i)
#pragma unroll
            for (int j = 0; j < FN; ++j) acc[i][j] = floatx4{0.f, 0.f, 0.f, 0.f};

        for (int kt = 0; kt < NK; ++kt) {
            const int k0 = kt * 64;
            __syncthreads();            // previous compute done reading LDS
#pragma unroll
            for (int j = 0; j < AI; ++j) dma16(asrc[j] + k0, adst[j]);
#pragma unroll
            for (int j = 0; j < WI; ++j) dma16(wsrc[j] + k0, wdst[j]);
            __syncthreads();            // drains vmcnt -> tiles visible
#pragma unroll
            for (int kk = 0; kk < 2; ++kk) {
                short8 av[FM], wv[FN];
#pragma unroll
                for (int i = 0; i < FM; ++i) {
                    int m = wy * FM * 16 + i * 16 + lm;
                    int pc = (kk * 4 + quad) ^ (m & 7);
                    av[i] = *(const short8*)&As[m * 64 + pc * 8];
                }
#pragma unroll
                for (int j = 0; j < FN; ++j) {
                    int n = wx * FN * 16 + j * 16 + lm;
                    int pc = (kk * 4 + quad) ^ (n & 7);
                    wv[j] = *(const short8*)&Ws[n * 64 + pc * 8];
                }
#pragma unroll
                for (int i = 0; i < FM; ++i)
#pragma unroll
                    for (int j = 0; j < FN; ++j)
                        acc[i][j] = __builtin_amdgcn_mfma_f32_16x16x32_bf16(
                            av[i], wv[j], acc[i][j], 0, 0, 0);
            }
        }

        // epilogue: bias + relu; C layout col=lane&15, row=quad*4+reg
#pragma unroll
        for (int i = 0; i < FM; ++i) {
#pragma unroll
            for (int rg = 0; rg < 4; ++rg) {
                int m = wy * FM * 16 + i * 16 + quad * 4 + rg;
                int p = row_start + m;
                if (p < bend) {
                    if constexpr (SCATTER) {
                        int orow = rowidx[p];
#pragma unroll
                        for (int j = 0; j < FN; ++j) {
                            int n = n0 + wx * FN * 16 + j * 16 + lm;
                            float v = acc[i][j][rg] + bias[j];
                            OutF[(size_t)orow * N + n] = v > 0.f ? v : 0.f;
                        }
                    } else {
#pragma unroll
                        for (int j = 0; j < FN; ++j) {
                            int n = n0 + wx * FN * 16 + j * 16 + lm;
                            float v = acc[i][j][rg] + bias[j];
                            OutB[(size_t)p * N + n] = f2bf(v > 0.f ? v : 0.f);
                        }
                    }
                }
            }
        }
    }
}

extern "C" void kernel_launch(void* const* d_in, const int* in_sizes, int n_in,
                              void* d_out, int out_size, void* d_ws, size_t ws_size,
                              hipStream_t stream) {
    const float* x = (const float*)d_in[0];
    const int* ind = (const int*)d_in[1];
    const float* sk0 = (const float*)d_in[2];
    const float* sb0 = (const float*)d_in[3];
    const float* dk0 = (const float*)d_in[4];
    const float* db0 = (const float*)d_in[5];
    const float* sk1 = (const float*)d_in[6];
    const float* sb1 = (const float*)d_in[7];
    const float* dk1 = (const float*)d_in[8];
    const float* db1 = (const float*)d_in[9];
    const float* sk2 = (const float*)d_in[10];
    const float* sb2 = (const float*)d_in[11];
    const float* dk2 = (const float*)d_in[12];
    const float* db2 = (const float*)d_in[13];
    float* out = (float*)d_out;

    // workspace layout (~46 MB)
    char* ws = (char*)d_ws;
    int* offsets = (int*)ws;                                      // 64 B
    int* rowidx = (int*)(ws + 256);                               // 16 KB
    unsigned short* xb  = (unsigned short*)(ws + 32768);          // 8 MB  bf16 x, bucket order
    unsigned short* h1  = xb + (size_t)NROWS * 1024;              // 8 MB
    unsigned short* h2  = h1 + (size_t)NROWS * 1024;              // 4 MB
    unsigned short* w0t = h2 + (size_t)NROWS * 512;               // 16 MB [d][n=1024][k=1024]
    unsigned short* w1t = w0t + (size_t)NDOM * 1024 * 1024;       // 8 MB  [d][n=512][k=1024]
    unsigned short* w2t = w1t + (size_t)NDOM * 512 * 1024;        // 2 MB  [d][n=256][k=512]

    bucket_kernel<<<1, 256, 0, stream>>>(ind, offsets, rowidx);
    precompute_kernel<<<256 + 2048 + 1024 + 256, 256, 0, stream>>>(
        x, rowidx, sk0, dk0, sk1, dk1, sk2, dk2, xb, w0t, w1t, w2t);

    // L0: 64x64 tiles, 8d x 8m x 16n = 1024 blocks (4/CU)
    star_gemm<2, 2, 8, 1024, 1024, false><<<1024, 256, 0, stream>>>(
        xb, w0t, sb0, db0, nullptr, h1, offsets, rowidx);
    // L1: 64x64 tiles, 8d x 8m x 8n = 512 blocks
    star_gemm<2, 2, 8, 1024, 512, false><<<512, 256, 0, stream>>>(
        h1, w1t, sb1, db1, nullptr, h2, offsets, rowidx);
    // L2: 32x64 tiles, 8d x 16m x 4n = 512 blocks (scatter to fp32 out)
    star_gemm<1, 2, 16, 512, 256, true><<<512, 256, 0, stream>>>(
        h2, w2t, sb2, db2, out, nullptr, offsets, rowidx);
}

// Round 6
// 187.625 us; speedup vs baseline: 1.5554x; 1.0996x over previous
//
#include <hip/hip_runtime.h>

#define NROWS 4096
#define NDOM 8

typedef short short8 __attribute__((ext_vector_type(8)));
typedef float floatx4 __attribute__((ext_vector_type(4)));
typedef unsigned short ushort8v __attribute__((ext_vector_type(8)));

__device__ __forceinline__ unsigned short f2bf(float f) {
    union { float f; unsigned u; } v; v.f = f;
    unsigned r = v.u + 0x7FFFu + ((v.u >> 16) & 1u);  // RNE
    return (unsigned short)(r >> 16);
}

// async global->LDS, 16B per lane; dest = wave-uniform base + lane*16,
// source address may be per-lane (gather is legal on the source side).
__device__ __forceinline__ void dma16(const void* g, void* l) {
    __builtin_amdgcn_global_load_lds(
        (const __attribute__((address_space(1))) unsigned*)g,
        (__attribute__((address_space(3))) unsigned*)l, 16, 0, 0);
}

// ---------------------------------------------------------------------------
// Fused precompute dispatch:
//   blocks [0,256)        : xb = bf16(x), ORIGINAL row order (no rowidx dep)
//   blocks [256,768)      : w0t = bf16(sk0*dk0) transposed [d][n][k]
//   blocks [768,1024)     : w1t
//   blocks [1024,1088)    : w2t
//   block 1088            : deterministic counting-sort -> offsets, rowidx
// Weight tiles are transposed through LDS so global stores are coalesced
// (4 x 512B contiguous segments per wave instead of 64 x 32B scatter).
// ---------------------------------------------------------------------------

template <int K, int N>
__device__ __forceinline__ void weff_tile(const float* __restrict__ sk,
                                          const float* __restrict__ dk,
                                          unsigned short* __restrict__ wt,
                                          unsigned short* __restrict__ lds,
                                          int local) {
    // tile = (domain d, 64 n, 256 k)
    const int d = local & 7;
    const int rest = local >> 3;
    const int k0 = (rest & (K / 256 - 1)) * 256;
    const int n0 = (rest / (K / 256)) * 64;
    const int t = threadIdx.x;

    // phase A: read n-coalesced, write LDS [n][k] with chunk-XOR swizzle
    const int n = t & 63;
    const int kg = (t >> 6) * 64;          // 4 k-groups of 64
#pragma unroll
    for (int c8 = 0; c8 < 8; ++c8) {       // 8 chunks of 8 k
        const int kb = k0 + kg + c8 * 8;
        unsigned short wb[8];
#pragma unroll
        for (int i = 0; i < 8; ++i) {
            int k = kb + i;
            wb[i] = f2bf(sk[(size_t)k * N + n0 + n] * dk[((size_t)d * K + k) * N + n0 + n]);
        }
        int ch = (kg + c8 * 8) >> 3;       // chunk index 0..31
        int phys = ch ^ (n & 31);
        *(ushort8v*)&lds[n * 256 + phys * 8] = *(ushort8v*)wb;
    }
    __syncthreads();

    // phase B: read LDS along k, store global [n][k] coalesced
#pragma unroll
    for (int it = 0; it < 4; ++it) {
        const int nn = (t >> 4) + it * 16;
        const int c = t & 15;              // 32B unit = 2 chunks
        ushort8v a = *(ushort8v*)&lds[nn * 256 + ((2 * c) ^ (nn & 31)) * 8];
        ushort8v b = *(ushort8v*)&lds[nn * 256 + ((2 * c + 1) ^ (nn & 31)) * 8];
        unsigned short* dst = wt + ((size_t)d * N + n0 + nn) * K + k0 + c * 16;
        *(ushort8v*)dst = a;
        *(ushort8v*)(dst + 8) = b;
    }
}

__global__ void precompute_kernel(const float* __restrict__ x,
                                  const int* __restrict__ ind,
                                  const float* __restrict__ sk0, const float* __restrict__ dk0,
                                  const float* __restrict__ sk1, const float* __restrict__ dk1,
                                  const float* __restrict__ sk2, const float* __restrict__ dk2,
                                  unsigned short* __restrict__ xb,
                                  unsigned short* __restrict__ w0t,
                                  unsigned short* __restrict__ w1t,
                                  unsigned short* __restrict__ w2t,
                                  int* __restrict__ offsets,
                                  int* __restrict__ rowidx) {
    __shared__ unsigned short wtile[64 * 256];      // 32KB transpose buffer
    __shared__ unsigned short cnt[256][NDOM];
    __shared__ int base[256][NDOM];
    __shared__ int dom_total[NDOM];
    __shared__ int dom_off[NDOM + 1];

    const int b = blockIdx.x;
    const int t = threadIdx.x;

    if (b < 256) {
        // xb: bf16(x) in original row order, fully coalesced both sides
#pragma unroll
        for (int pass = 0; pass < 8; ++pass) {
            int row = b * 16 + pass * 2 + (t >> 7);
            int ch = t & 127;                       // 8-elem chunk
            const float* src = x + (size_t)row * 1024 + ch * 8;
            floatx4 v0 = *(const floatx4*)src;
            floatx4 v1 = *(const floatx4*)(src + 4);
            unsigned short o[8];
            o[0] = f2bf(v0[0]); o[1] = f2bf(v0[1]); o[2] = f2bf(v0[2]); o[3] = f2bf(v0[3]);
            o[4] = f2bf(v1[0]); o[5] = f2bf(v1[1]); o[6] = f2bf(v1[2]); o[7] = f2bf(v1[3]);
            *(ushort8v*)(xb + (size_t)row * 1024 + ch * 8) = *(ushort8v*)o;
        }
    } else if (b < 256 + 512) {
        weff_tile<1024, 1024>(sk0, dk0, w0t, wtile, b - 256);
    } else if (b < 256 + 512 + 256) {
        weff_tile<1024, 512>(sk1, dk1, w1t, wtile, b - (256 + 512));
    } else if (b < 256 + 512 + 256 + 64) {
        weff_tile<512, 256>(sk2, dk2, w2t, wtile, b - (256 + 512 + 256));
    } else {
        // deterministic stable counting sort (pure function of `ind`)
        int myind[16];
#pragma unroll
        for (int i = 0; i < 16; ++i) myind[i] = ind[t * 16 + i];
        unsigned short c[NDOM];
#pragma unroll
        for (int d = 0; d < NDOM; ++d) c[d] = 0;
#pragma unroll
        for (int i = 0; i < 16; ++i) c[myind[i]]++;
#pragma unroll
        for (int d = 0; d < NDOM; ++d) cnt[t][d] = c[d];
        __syncthreads();
        if (t < NDOM) {
            int acc = 0;
            for (int ch = 0; ch < 256; ++ch) { base[ch][t] = acc; acc += cnt[ch][t]; }
            dom_total[t] = acc;
        }
        __syncthreads();
        if (t == 0) {
            int acc = 0;
            for (int d = 0; d < NDOM; ++d) { dom_off[d] = acc; acc += dom_total[d]; }
            dom_off[NDOM] = acc;
        }
        __syncthreads();
        int pos[NDOM];
#pragma unroll
        for (int d = 0; d < NDOM; ++d) pos[d] = dom_off[d] + base[t][d];
#pragma unroll
        for (int i = 0; i < 16; ++i) {
            int dm = myind[i];
            rowidx[pos[dm]++] = t * 16 + i;
        }
        if (t <= NDOM) offsets[t] = dom_off[t];
    }
}

// ---------------------------------------------------------------------------
// Grouped GEMM: 2x2 waves, wave tile (FM*16)x(FN*16), double-buffered LDS,
// one barrier per k-tile. Frag ds_reads are hoisted BEFORE the next tile's
// DMA issue so no conservative vmcnt wait can land mid-loop; the barrier's
// vmcnt(0) drain waits only for latency not covered by the compute phase.
// A source is per-lane (rowidx-gathered for L0); LDS chunk-XOR swizzle is
// applied on the DMA source address (dest is forced lane*16).
// ---------------------------------------------------------------------------
template <int FM, int FN, int MSLOTS, int K, int N, bool GATHER, bool SCATTER>
__launch_bounds__(256)
__global__ void star_gemm(const unsigned short* __restrict__ Ab,
                          const unsigned short* __restrict__ Wt,
                          const float* __restrict__ sb,
                          const float* __restrict__ db,
                          float* __restrict__ OutF,
                          unsigned short* __restrict__ OutB,
                          const int* __restrict__ offsets,
                          const int* __restrict__ rowidx) {
    constexpr int BM = 32 * FM;
    constexpr int BN = 32 * FN;
    constexpr int NK = K / 64;     // 64-wide k tiles (NK even)
    constexpr int AI = BM / 32;    // A dma instrs per wave (1KB each)
    constexpr int WI = BN / 32;    // W dma instrs per wave

    __shared__ __align__(128) unsigned short As[2][BM * 64];
    __shared__ __align__(128) unsigned short Ws[2][BN * 64];

    const int gid = blockIdx.x;
    const int d = gid & 7;                      // domain -> XCD round-robin
    const int mslot = (gid >> 3) % MSLOTS;
    const int n0 = (gid / (8 * MSLOTS)) * BN;

    const int bstart = offsets[d];
    const int bend = offsets[d + 1];
    const int bsize = bend - bstart;

    const int tid = threadIdx.x;
    const int lane = tid & 63;
    const int w = tid >> 6;
    const int wy = w >> 1;
    const int wx = w & 1;
    const int lm = lane & 15;
    const int quad = lane >> 4;

    const int lrow = lane >> 3;    // DMA: row within 8-row group
    const int phys = lane & 7;     // DMA: physical LDS chunk

    float bias[FN];
#pragma unroll
    for (int j = 0; j < FN; ++j) {
        int n = n0 + wx * FN * 16 + j * 16 + lm;
        bias[j] = sb[n] + db[d * N + n];
    }

    // W dma sources (loop-invariant)
    const unsigned short* wsrc[WI];
#pragma unroll
    for (int j = 0; j < WI; ++j) {
        int nr0 = (w * WI + j) * 8;
        int nn = nr0 + lrow;
        int ch = phys ^ (nn & 7);
        wsrc[j] = Wt + ((size_t)d * N + n0 + nn) * K + ch * 8;
    }

    for (int mt = mslot; mt * BM < bsize; mt += MSLOTS) {
        const int row_start = bstart + mt * BM;

        const unsigned short* asrc[AI];
#pragma unroll
        for (int j = 0; j < AI; ++j) {
            int m0 = (w * AI + j) * 8;
            int mm = m0 + lrow;
            int ch = phys ^ (mm & 7);
            int p = row_start + mm; if (p >= bend) p = bend - 1;
            int src = GATHER ? rowidx[p] : p;
            asrc[j] = Ab + (size_t)src * K + ch * 8;
        }

        auto dma_tiles = [&](int kt, int buf) {
            const int k0 = kt * 64;
#pragma unroll
            for (int j = 0; j < AI; ++j)
                dma16(asrc[j] + k0, &As[buf][(w * AI + j) * 512]);
#pragma unroll
            for (int j = 0; j < WI; ++j)
                dma16(wsrc[j] + k0, &Ws[buf][(w * WI + j) * 512]);
        };

        floatx4 acc[FM][FN];
#pragma unroll
        for (int i = 0; i < FM; ++i)
#pragma unroll
            for (int j = 0; j < FN; ++j) acc[i][j] = floatx4{0.f, 0.f, 0.f, 0.f};

        dma_tiles(0, 0);                       // prologue (buf0 safe: see barrier layout)
        for (int kt = 0; kt < NK; ++kt) {
            const int buf = kt & 1;
            __syncthreads();                   // drains dma(kt); prev compute done

            // hoist ALL frag reads before issuing next DMA
            short8 av[2][FM], wv[2][FN];
#pragma unroll
            for (int kk = 0; kk < 2; ++kk) {
#pragma unroll
                for (int i = 0; i < FM; ++i) {
                    int m = wy * FM * 16 + i * 16 + lm;
                    int pc = (kk * 4 + quad) ^ (m & 7);
                    av[kk][i] = *(const short8*)&As[buf][m * 64 + pc * 8];
                }
#pragma unroll
                for (int j = 0; j < FN; ++j) {
                    int n = wx * FN * 16 + j * 16 + lm;
                    int pc = (kk * 4 + quad) ^ (n & 7);
                    wv[kk][j] = *(const short8*)&Ws[buf][n * 64 + pc * 8];
                }
            }
            if (kt + 1 < NK) dma_tiles(kt + 1, 1 - buf);   // in flight across MFMA
#pragma unroll
            for (int kk = 0; kk < 2; ++kk)
#pragma unroll
                for (int i = 0; i < FM; ++i)
#pragma unroll
                    for (int j = 0; j < FN; ++j)
                        acc[i][j] = __builtin_amdgcn_mfma_f32_16x16x32_bf16(
                            av[kk][i], wv[kk][j], acc[i][j], 0, 0, 0);
        }

        // epilogue: bias + relu; C layout col=lane&15, row=quad*4+reg
#pragma unroll
        for (int i = 0; i < FM; ++i) {
#pragma unroll
            for (int rg = 0; rg < 4; ++rg) {
                int m = wy * FM * 16 + i * 16 + quad * 4 + rg;
                int p = row_start + m;
                if (p < bend) {
                    if constexpr (SCATTER) {
                        int orow = rowidx[p];
#pragma unroll
                        for (int j = 0; j < FN; ++j) {
                            int n = n0 + wx * FN * 16 + j * 16 + lm;
                            float v = acc[i][j][rg] + bias[j];
                            OutF[(size_t)orow * N + n] = v > 0.f ? v : 0.f;
                        }
                    } else {
#pragma unroll
                        for (int j = 0; j < FN; ++j) {
                            int n = n0 + wx * FN * 16 + j * 16 + lm;
                            float v = acc[i][j][rg] + bias[j];
                            OutB[(size_t)p * N + n] = f2bf(v > 0.f ? v : 0.f);
                        }
                    }
                }
            }
        }
    }
}

extern "C" void kernel_launch(void* const* d_in, const int* in_sizes, int n_in,
                              void* d_out, int out_size, void* d_ws, size_t ws_size,
                              hipStream_t stream) {
    const float* x = (const float*)d_in[0];
    const int* ind = (const int*)d_in[1];
    const float* sk0 = (const float*)d_in[2];
    const float* sb0 = (const float*)d_in[3];
    const float* dk0 = (const float*)d_in[4];
    const float* db0 = (const float*)d_in[5];
    const float* sk1 = (const float*)d_in[6];
    const float* sb1 = (const float*)d_in[7];
    const float* dk1 = (const float*)d_in[8];
    const float* db1 = (const float*)d_in[9];
    const float* sk2 = (const float*)d_in[10];
    const float* sb2 = (const float*)d_in[11];
    const float* dk2 = (const float*)d_in[12];
    const float* db2 = (const float*)d_in[13];
    float* out = (float*)d_out;

    // workspace layout (~46 MB)
    char* ws = (char*)d_ws;
    int* offsets = (int*)ws;                                      // 64 B
    int* rowidx = (int*)(ws + 256);                               // 16 KB
    unsigned short* xb  = (unsigned short*)(ws + 32768);          // 8 MB  bf16 x, ORIGINAL order
    unsigned short* h1  = xb + (size_t)NROWS * 1024;              // 8 MB  bucket order
    unsigned short* h2  = h1 + (size_t)NROWS * 1024;              // 4 MB  bucket order
    unsigned short* w0t = h2 + (size_t)NROWS * 512;               // 16 MB [d][n=1024][k=1024]
    unsigned short* w1t = w0t + (size_t)NDOM * 1024 * 1024;       // 8 MB  [d][n=512][k=1024]
    unsigned short* w2t = w1t + (size_t)NDOM * 512 * 1024;        // 2 MB  [d][n=256][k=512]

    // fused: xb cvt + 3x weight transpose-precompute + bucket sort (1 dispatch)
    precompute_kernel<<<256 + 512 + 256 + 64 + 1, 256, 0, stream>>>(
        x, ind, sk0, dk0, sk1, dk1, sk2, dk2, xb, w0t, w1t, w2t, offsets, rowidx);

    // L0: 64x64 tiles, 8d x 8m x 16n = 1024 blocks, rowidx-gather DMA
    star_gemm<2, 2, 8, 1024, 1024, true, false><<<1024, 256, 0, stream>>>(
        xb, w0t, sb0, db0, nullptr, h1, offsets, rowidx);
    // L1: 64x64 tiles, 8d x 8m x 8n = 512 blocks
    star_gemm<2, 2, 8, 1024, 512, false, false><<<512, 256, 0, stream>>>(
        h1, w1t, sb1, db1, nullptr, h2, offsets, rowidx);
    // L2: 32x64 tiles, 8d x 16m x 4n = 512 blocks (scatter to fp32 out)
    star_gemm<1, 2, 16, 512, 256, false, true><<<512, 256, 0, stream>>>(
        h2, w2t, sb2, db2, out, nullptr, offsets, rowidx);
}